// Round 8
// baseline (690.876 us; speedup 1.0000x reference)
//
#include <hip/hip_runtime.h>
#include <math.h>

typedef unsigned short u16;
typedef unsigned int   u32;
typedef __attribute__((ext_vector_type(8))) _Float16 half8;
typedef __attribute__((ext_vector_type(4))) float    f32x4;

#define PI_F 3.14159265358979323846f

__device__ __forceinline__ float lrelu_f(float x){ return x >= 0.f ? x : 0.05f*x; }
__device__ __forceinline__ u16 f2h(float f){ _Float16 h = (_Float16)f; u16 u; __builtin_memcpy(&u,&h,2); return u; }
__device__ __forceinline__ float h2f(u16 u){ _Float16 h; __builtin_memcpy(&h,&u,2); return (float)h; }

// ---------------------------------------------------------------------------
// Stage-0 index map: xu flat (oh,ow,kh,kw) -> lat*W + lon (grid_sample == gather)
// ---------------------------------------------------------------------------
__global__ void k_idxmap(int* __restrict__ map, int H, int W, int Wo, int total)
{
    int i = blockIdx.x*blockDim.x + threadIdx.x;
    if (i >= total) return;
    int oh  = i / (Wo*9);
    int rem = i % (Wo*9);
    int ow  = rem / 9;
    int r2  = rem % 9;
    int kh  = r2/3, kw = r2%3;
    int ihc = min(oh*2, H-1);
    int lat = min(max(ihc + kh - 1, 0), H-1);
    float phi = ((float)lat + 0.5f)/(float)H * PI_F - 0.5f*PI_F;
    float ca  = fmaxf(fabsf(cosf(phi)), 1e-3f);
    float d   = fminf(0.8f/ca, 4.0f);
    float jw  = (float)((ow*2) % W);
    float lonf = rintf(jw + d*(float)(kw-1));
    int lon = (int)lonf % W; if (lon < 0) lon += W;
    map[i] = lat*W + lon;
}

// ---------------------------------------------------------------------------
// Fused im2col index tables (R7 post-mortem: staging decode was ~80 VALU
// ops/element — 5 non-pow2 div/mods; bake them into a one-time int table).
// fmap[(oh*NPAD + n)*KP + k] = within-batch input offset, or -1 for k-pad.
// ---------------------------------------------------------------------------
__global__ void k_fmap_sph(const int* __restrict__ map, int* __restrict__ fmap,
                           int OH, int NPAD, int K, int KP, int RW, int IPLANE)
{
    int i = blockIdx.x*blockDim.x + threadIdx.x;
    int total = OH*NPAD*KP;
    if (i >= total) return;
    int k   = i % KP;
    int r   = i / KP;
    int n   = r % NPAD;
    int oh  = r / NPAD;
    int idx = -1;
    if (k < K){
        int ci = k/25, r2 = k%25, u = r2/5, v = r2%5;
        int c = n*3 + v; c = min(c, RW-1);
        idx = ci*IPLANE + map[(oh*3+u)*RW + c];
    }
    fmap[i] = idx;
}

__global__ void k_fmap_dir(int* __restrict__ fmap,
                           int OH, int NPAD, int K, int KPQ, int KW, int S,
                           int IH, int IW)
{
    int i = blockIdx.x*blockDim.x + threadIdx.x;
    int total = OH*NPAD*K;
    if (i >= total) return;
    int k   = i % K;
    int r   = i / K;
    int n   = r % NPAD;
    int oh  = r / NPAD;
    int ci = k/KPQ, r2 = k%KPQ, p = r2/KW, q = r2%KW;
    int row = oh*S + p;
    int col = min(n*S + q, IW-1);
    fmap[i] = (ci*IH + row)*IW + col;
}

// ---------------------------------------------------------------------------
// Sphere weights: fold avg_pool3(conv3x3) into 5x5/stride3, f16 [co][KP]
// ---------------------------------------------------------------------------
__global__ void k_w5h(const float* __restrict__ w3, u16* __restrict__ wh,
                      int CO, int CI, int KP)
{
    int i = blockIdx.x*blockDim.x + threadIdx.x;
    if (i >= CO*KP) return;
    int k = i % KP, co = i / KP;
    float s = 0.f;
    if (k < CI*25){
        int ci = k/25, rem = k%25, u = rem/5, v = rem%5;
        const float* w = w3 + (co*CI + ci)*9;
        int p0 = max(0, u-2), p1 = min(2, u);
        int q0 = max(0, v-2), q1 = min(2, v);
        for (int p=p0;p<=p1;++p)
            for (int q=q0;q<=q1;++q) s += w[p*3+q];
        s *= (1.0f/9.0f);
    }
    wh[i] = f2h(s);
}

// plain OIHW fp32 -> f16
__global__ void k_wcvt(const float* __restrict__ w, u16* __restrict__ wh, int total)
{
    int i = blockIdx.x*blockDim.x + threadIdx.x;
    if (i < total) wh[i] = f2h(w[i]);
}

// ---------------------------------------------------------------------------
// Unified MFMA conv engine. Block = (b, oh); 4 waves; K-chunked LDS staging
// via precomputed fmap (coalesced int2 reads -> 2 gathers -> packed write).
// Fragment layout (guide §3, m89-verified): A/B lane&15 = M/N index,
// k=(lane>>4)*8+j; D col=lane&15, row=(lane>>4)*4+reg. KCp%8==0 keeps
// half8 reads 16B-aligned; row-stride bank aliasing is 2-way (free, m136).
// ---------------------------------------------------------------------------
template<typename IN_T,int CO,int OH,int OW,int BSTRIDE,
         int K,int KP,int KC,int KCp,int NT_N,int NT_CO>
__global__ __launch_bounds__(256) void k_mconv(
    const IN_T* __restrict__ in, const int* __restrict__ fmap,
    const u16* __restrict__ wh,
    const float* __restrict__ bg, const float* __restrict__ bb,
    const float* __restrict__ bm, const float* __restrict__ bv,
    u16* __restrict__ out)
{
    constexpr int NPAD = NT_N*16;
    constexpr int TPW  = (NT_N*NT_CO)/4;
    static_assert((NT_N*NT_CO) % 4 == 0, "tiles must split across 4 waves");
    static_assert(KCp % 8 == 0, "16B-aligned half8 rows");
    __shared__ __align__(16) u16 sA[NPAD*KCp];
    __shared__ __align__(16) u16 sB[CO*KCp];
    int b = blockIdx.x / OH, oh = blockIdx.x % OH;
    int tid = threadIdx.x;
    const IN_T* xb = in + (size_t)b*BSTRIDE;
    const int*  fm = fmap + (size_t)oh*NPAD*KP;
    int w = tid >> 6, lane = tid & 63, l15 = lane & 15, l4 = lane >> 4;
    int nt = w % NT_N;
    f32x4 acc[TPW];
    #pragma unroll
    for (int j=0;j<TPW;++j) acc[j] = (f32x4){0.f,0.f,0.f,0.f};

    for (int kc0 = 0; kc0 < KP; kc0 += KC){
        if (kc0) __syncthreads();
        // stage A: im2col gather via fmap, 2 elements/thread/iter
        constexpr int PAIRS = NPAD*(KC/2);
        for (int i = tid; i < PAIRS; i += 256){
            int n  = i / (KC/2);
            int kl = (i % (KC/2))*2;
            int2 ix = *reinterpret_cast<const int2*>(fm + n*KP + kc0 + kl);
            u16 v0, v1;
            if constexpr (KP != K){
                v0 = 0; v1 = 0;
                if (ix.x >= 0){ if constexpr (sizeof(IN_T)==4) v0 = f2h(xb[ix.x]); else v0 = xb[ix.x]; }
                if (ix.y >= 0){ if constexpr (sizeof(IN_T)==4) v1 = f2h(xb[ix.y]); else v1 = xb[ix.y]; }
            } else {
                if constexpr (sizeof(IN_T)==4){ v0 = f2h(xb[ix.x]); v1 = f2h(xb[ix.y]); }
                else                          { v0 = xb[ix.x];      v1 = xb[ix.y]; }
            }
            *reinterpret_cast<u32*>(&sA[n*KCp + kl]) = (u32)v0 | ((u32)v1 << 16);
        }
        // stage B: weights, contiguous 16B copies
        for (int i = tid; i < CO*KC/8; i += 256){
            int co = i / (KC/8), j = i % (KC/8);
            uint4 v = *reinterpret_cast<const uint4*>(wh + (size_t)co*KP + kc0 + j*8);
            *reinterpret_cast<uint4*>(&sB[co*KCp + j*8]) = v;
        }
        __syncthreads();
        #pragma unroll
        for (int ks = 0; ks < KC/32; ++ks){
            half8 a = *reinterpret_cast<const half8*>(&sA[(nt*16 + l15)*KCp + ks*32 + l4*8]);
            #pragma unroll
            for (int j=0;j<TPW;++j){
                int ct = (w + j*4)/NT_N;
                half8 bf = *reinterpret_cast<const half8*>(&sB[(ct*16 + l15)*KCp + ks*32 + l4*8]);
                acc[j] = __builtin_amdgcn_mfma_f32_16x16x32_f16(a, bf, acc[j], 0, 0, 0);
            }
        }
    }
    #pragma unroll
    for (int j=0;j<TPW;++j){
        int ct = (w + j*4)/NT_N;
        int co = ct*16 + l15;
        float inv = bg[co]*rsqrtf(bv[co]+1e-5f);
        float shv = bb[co] - bm[co]*inv;
        int n0 = nt*16 + l4*4;
        size_t ob = ((size_t)(b*CO + co)*OH + oh)*OW;
        #pragma unroll
        for (int r=0;r<4;++r){
            int n = n0 + r;
            if (n < OW) out[ob + n] = f2h(lrelu_f(fmaf(acc[j][r], inv, shv)));
        }
    }
}

// ---------------------------------------------------------------------------
// fused = lrelu(h5_flat @ proj_w.T + v @ vproj_w.T + vproj_b)   (h5 is f16)
// ---------------------------------------------------------------------------
__global__ __launch_bounds__(256) void k_head(
    const u16* __restrict__ h5, const float* __restrict__ vin,
    const float* __restrict__ proj_w, const float* __restrict__ vproj_w,
    const float* __restrict__ vproj_b, float* __restrict__ fused)
{
    __shared__ __align__(16) float sh[2560];
    __shared__ float sv[9];
    int b = blockIdx.x, tid = threadIdx.x;
    for (int i = tid; i < 2560; i += 256) sh[i] = h2f(h5[(size_t)b*2560 + i]);
    if (tid < 9) sv[tid] = vin[b*9 + tid];
    __syncthreads();
    const float* pw = proj_w + (size_t)tid*2560;
    float acc = 0.f;
    for (int k=0;k<2560;k+=4){
        float4 s4 = *reinterpret_cast<const float4*>(sh+k);
        float4 w4 = *reinterpret_cast<const float4*>(pw+k);
        acc = fmaf(s4.x,w4.x, fmaf(s4.y,w4.y, fmaf(s4.z,w4.z, fmaf(s4.w,w4.w, acc))));
    }
    float av = 0.f;
    #pragma unroll
    for (int k=0;k<9;++k) av += sv[k]*vproj_w[tid*9+k];
    fused[b*256+tid] = lrelu_f(acc + av + vproj_b[tid]);
}

// ---------------------------------------------------------------------------
// GRU cell
// ---------------------------------------------------------------------------
__global__ __launch_bounds__(256) void k_gru(
    const float* __restrict__ fused, const float* __restrict__ hx,
    const float* __restrict__ wih, const float* __restrict__ whh,
    const float* __restrict__ bih, const float* __restrict__ bhh,
    float* __restrict__ hx_new)
{
    __shared__ __align__(16) float sf[256];
    __shared__ __align__(16) float shx[256];
    int b = blockIdx.x, j = threadIdx.x;
    sf[j]  = fused[b*256+j];
    shx[j] = hx[b*256+j];
    __syncthreads();
    float ga[3], gb[3];
    #pragma unroll
    for (int gi=0; gi<3; ++gi){
        const float* wi = wih + ((size_t)gi*256 + j)*256;
        const float* wh = whh + ((size_t)gi*256 + j)*256;
        float a = 0.f, c = 0.f;
        for (int k=0;k<256;k+=4){
            float4 f4  = *reinterpret_cast<const float4*>(sf+k);
            float4 h4  = *reinterpret_cast<const float4*>(shx+k);
            float4 wi4 = *reinterpret_cast<const float4*>(wi+k);
            float4 wh4 = *reinterpret_cast<const float4*>(wh+k);
            a = fmaf(f4.x,wi4.x, fmaf(f4.y,wi4.y, fmaf(f4.z,wi4.z, fmaf(f4.w,wi4.w, a))));
            c = fmaf(h4.x,wh4.x, fmaf(h4.y,wh4.y, fmaf(h4.z,wh4.z, fmaf(h4.w,wh4.w, c))));
        }
        ga[gi] = a + bih[gi*256+j];
        gb[gi] = c + bhh[gi*256+j];
    }
    float r = 1.f/(1.f+expf(-(ga[0]+gb[0])));
    float z = 1.f/(1.f+expf(-(ga[1]+gb[1])));
    float n = tanhf(ga[2] + r*gb[2]);
    hx_new[b*256+j] = (1.f-z)*n + z*shx[j];
}

// act = lrelu(hx_new) @ fc_w.T
__global__ void k_act(const float* __restrict__ hx_new, const float* __restrict__ fc_w,
                      float* __restrict__ act)
{
    int t = blockIdx.x*blockDim.x + threadIdx.x;
    if (t >= 1024) return;
    int b = t >> 2, o = t & 3;
    const float* h = hx_new + b*256;
    const float* w = fc_w + o*256;
    float acc = 0.f;
    for (int k=0;k<256;++k) acc = fmaf(lrelu_f(h[k]), w[k], acc);
    act[t] = acc;
}

extern "C" void kernel_launch(void* const* d_in, const int* in_sizes, int n_in,
                              void* d_out, int out_size, void* d_ws, size_t ws_size,
                              hipStream_t stream)
{
    const float* x      = (const float*)d_in[0];
    const float* vin    = (const float*)d_in[1];
    const float* hx     = (const float*)d_in[2];
    const float* sc0_w  = (const float*)d_in[3];
    const float* bn0g   = (const float*)d_in[4];
    const float* bn0b   = (const float*)d_in[5];
    const float* bn0m   = (const float*)d_in[6];
    const float* bn0v   = (const float*)d_in[7];
    const float* sc1_w  = (const float*)d_in[8];
    const float* bn1g   = (const float*)d_in[9];
    const float* bn1b   = (const float*)d_in[10];
    const float* bn1m   = (const float*)d_in[11];
    const float* bn1v   = (const float*)d_in[12];
    const float* c2_w   = (const float*)d_in[13];
    const float* bn2g   = (const float*)d_in[14];
    const float* bn2b   = (const float*)d_in[15];
    const float* bn2m   = (const float*)d_in[16];
    const float* bn2v   = (const float*)d_in[17];
    const float* c3_w   = (const float*)d_in[18];
    const float* bn3g   = (const float*)d_in[19];
    const float* bn3b   = (const float*)d_in[20];
    const float* bn3m   = (const float*)d_in[21];
    const float* bn3v   = (const float*)d_in[22];
    const float* c4_w   = (const float*)d_in[23];
    const float* bn4g   = (const float*)d_in[24];
    const float* bn4b   = (const float*)d_in[25];
    const float* bn4m   = (const float*)d_in[26];
    const float* bn4v   = (const float*)d_in[27];
    const float* c5_w   = (const float*)d_in[28];
    const float* bn5g   = (const float*)d_in[29];
    const float* bn5b   = (const float*)d_in[30];
    const float* bn5m   = (const float*)d_in[31];
    const float* bn5v   = (const float*)d_in[32];
    const float* proj_w = (const float*)d_in[33];
    const float* vproj_w= (const float*)d_in[34];
    const float* vproj_b= (const float*)d_in[35];
    const float* gru_wih= (const float*)d_in[36];
    const float* gru_whh= (const float*)d_in[37];
    const float* gru_bih= (const float*)d_in[38];
    const float* gru_bhh= (const float*)d_in[39];
    const float* fc_w   = (const float*)d_in[40];

    char* base = (char*)d_ws;
    size_t off = 0;
    auto alloc = [&](size_t bytes)->char*{
        char* p = base + off; off += (bytes + 255) & ~(size_t)255; return p;
    };
    int* map0  = (int*)alloc(96*192*4);
    int* map1  = (int*)alloc(48*96*4);
    int* fmap0 = (int*)alloc((size_t)31*64*160*4);
    int* fmap1 = (int*)alloc((size_t)15*32*800*4);
    int* fmap2 = (int*)alloc((size_t)13*32*576*4);
    int* fmap3 = (int*)alloc((size_t)6*16*256*4);
    int* fmap4 = (int*)alloc((size_t)4*16*576*4);
    int* fmap5 = (int*)alloc((size_t)2*16*1152*4);
    u16* wb0  = (u16*)alloc(32*160*2);
    u16* wb1  = (u16*)alloc(64*800*2);
    u16* wb2  = (u16*)alloc((size_t)64*576*2);
    u16* wb3  = (u16*)alloc((size_t)64*256*2);
    u16* wb4  = (u16*)alloc((size_t)128*576*2);
    u16* wb5  = (u16*)alloc((size_t)128*1152*2);
    u16* h0   = (u16*)alloc((size_t)256*32*1953*2);
    u16* h1   = (u16*)alloc((size_t)256*64*465*2);
    u16* h2   = (u16*)alloc((size_t)256*64*377*2);
    u16* h3   = (u16*)alloc((size_t)256*64*84*2);
    u16* h4   = (u16*)alloc((size_t)256*128*48*2);
    u16* h5   = (u16*)alloc((size_t)256*128*20*2);
    float* fused = (float*)alloc((size_t)65536*4);

    // one-time precompute: lat/lon maps -> fused im2col maps, f16 weights
    k_idxmap<<<72, 256, 0, stream>>>(map0, 64, 128, 64, 96*192);
    k_idxmap<<<18, 256, 0, stream>>>(map1, 31,  63, 32, 48*96);
    k_fmap_sph<<<(31*64*160+255)/256, 256, 0, stream>>>(map0, fmap0, 31, 64, 150, 160, 192, 8192);
    k_fmap_sph<<<(15*32*800+255)/256, 256, 0, stream>>>(map1, fmap1, 15, 32, 800, 800, 96, 1953);
    k_fmap_dir<<<(13*32*576+255)/256, 256, 0, stream>>>(fmap2, 13, 32, 576, 9, 3, 1, 15, 31);
    k_fmap_dir<<<(6*16*256 +255)/256, 256, 0, stream>>>(fmap3, 6, 16, 256, 4, 2, 2, 13, 29);
    k_fmap_dir<<<(4*16*576 +255)/256, 256, 0, stream>>>(fmap4, 4, 16, 576, 9, 3, 1, 6, 14);
    k_fmap_dir<<<(2*16*1152+255)/256, 256, 0, stream>>>(fmap5, 2, 16, 1152, 9, 3, 1, 4, 12);
    k_w5h<<<(32*160 +255)/256, 256, 0, stream>>>(sc0_w, wb0, 32, 6, 160);
    k_w5h<<<(64*800 +255)/256, 256, 0, stream>>>(sc1_w, wb1, 64, 32, 800);
    k_wcvt<<<(36864 +255)/256, 256, 0, stream>>>(c2_w, wb2, 36864);
    k_wcvt<<<(16384 +255)/256, 256, 0, stream>>>(c3_w, wb3, 16384);
    k_wcvt<<<(73728 +255)/256, 256, 0, stream>>>(c4_w, wb4, 73728);
    k_wcvt<<<(147456+255)/256, 256, 0, stream>>>(c5_w, wb5, 147456);

    // backbone (MFMA f16, fmap-staged)
    // k_mconv<IN_T,CO,OH,OW,BSTRIDE,K,KP,KC,KCp,NT_N,NT_CO>
    k_mconv<float,32,31,63,49152,150,160,160,168,4,2>
        <<<256*31, 256, 0, stream>>>(x,  fmap0, wb0, bn0g,bn0b,bn0m,bn0v, h0);
    k_mconv<u16,64,15,31,62496,800,800,160,168,2,4>
        <<<256*15, 256, 0, stream>>>(h0, fmap1, wb1, bn1g,bn1b,bn1m,bn1v, h1);
    k_mconv<u16,64,13,29,29760,576,576,192,200,2,4>
        <<<256*13, 256, 0, stream>>>(h1, fmap2, wb2, bn2g,bn2b,bn2m,bn2v, h2);
    k_mconv<u16,64,6,14,24128,256,256,128,136,1,4>
        <<<256*6,  256, 0, stream>>>(h2, fmap3, wb3, bn3g,bn3b,bn3m,bn3v, h3);
    k_mconv<u16,128,4,12,5376,576,576,96,104,1,8>
        <<<256*4,  256, 0, stream>>>(h3, fmap4, wb4, bn4g,bn4b,bn4m,bn4v, h4);
    k_mconv<u16,128,2,10,6144,1152,1152,96,104,1,8>
        <<<256*2,  256, 0, stream>>>(h4, fmap5, wb5, bn5g,bn5b,bn5m,bn5v, h5);

    // head
    k_head<<<256, 256, 0, stream>>>(h5, vin, proj_w, vproj_w, vproj_b, fused);
    float* outp = (float*)d_out;
    k_gru<<<256, 256, 0, stream>>>(fused, hx, gru_wih, gru_whh, gru_bih, gru_bhh, outp + 1024);
    k_act<<<4, 256, 0, stream>>>(outp + 1024, fc_w, outp);
}

// Round 10
// 600.859 us; speedup vs baseline: 1.1498x; 1.1498x over previous
//
#include <hip/hip_runtime.h>
#include <math.h>

typedef unsigned short u16;
typedef unsigned int   u32;
typedef __attribute__((ext_vector_type(8))) _Float16 half8;
typedef __attribute__((ext_vector_type(4))) float    f32x4;

#define PI_F 3.14159265358979323846f

__device__ __forceinline__ float lrelu_f(float x){ return x >= 0.f ? x : 0.05f*x; }
__device__ __forceinline__ u16 f2h(float f){ _Float16 h = (_Float16)f; u16 u; __builtin_memcpy(&u,&h,2); return u; }
__device__ __forceinline__ float h2f(u16 u){ _Float16 h; __builtin_memcpy(&h,&u,2); return (float)h; }

// ---------------------------------------------------------------------------
// Fused im2col index tables, K-MAJOR [KP][NTOTP]. Pad entries -> 0 (pad-k
// columns are killed by zero-padded WEIGHTS, pad-n rows by the write guard).
//
// R9 post-mortem: the xu "image" is a C-ORDER RESHAPE of (H_out,W_out,3,3)
// into (H_out*3, W_out*3). Rows do NOT decompose as (oh*3+kh); the only valid
// inversion is through the flat index:
//   flat = r*(Wo*3)+c; oh=flat/(Wo*9); rem=flat%(Wo*9); ow=rem/9;
//   kh=(rem%9)/3; kw=rem%3.
// (R0-R8's k_idxmap did exactly this; R9 inlined a blockwise decode -> FAIL.)
// ---------------------------------------------------------------------------
struct SphP { int* fmap; int OW,NTOT,NTOTP,K,KP,Wo,H,W,IPLANE,total; };

__global__ void k_fmap_sph2(SphP p0, SphP p1)
{
    SphP p = blockIdx.y ? p1 : p0;
    int i = blockIdx.x*blockDim.x + threadIdx.x;
    if (i >= p.total) return;
    int n = i % p.NTOTP, k = i / p.NTOTP;
    int val = 0;
    if (n < p.NTOT && k < p.K){
        int ohc = n / p.OW, owc = n % p.OW;          // 5x5/stride-3 conv output pos
        int ci = k/25, r2 = k - ci*25, u = r2/5, v = r2 - u*5;
        int r = ohc*3 + u;                            // xu image row
        int c = owc*3 + v;                            // xu image col (in-range by construction)
        int flat = r*(p.Wo*3) + c;                    // C-order reshape inversion
        int ohg  = flat / (p.Wo*9);
        int rem  = flat % (p.Wo*9);
        int owg  = rem / 9;
        int r3   = rem % 9;
        int kh   = r3/3, kw = r3 - (r3/3)*3;
        int ihc = min(ohg*2, p.H-1);
        int lat = min(max(ihc + kh - 1, 0), p.H-1);
        float phi = ((float)lat + 0.5f)/(float)p.H * PI_F - 0.5f*PI_F;
        float ca  = fmaxf(fabsf(cosf(phi)), 1e-3f);
        float d   = fminf(0.8f/ca, 4.0f);
        float jw  = (float)((owg*2) % p.W);
        float lonf = rintf(jw + d*(float)(kw-1));     // np.round == rint (half-even)
        int lon = (int)lonf % p.W; if (lon < 0) lon += p.W;
        val = ci*p.IPLANE + lat*p.W + lon;
    }
    p.fmap[i] = val;
}

struct DirP { int* fmap; int OW,NTOT,NTOTP,K,KPQ,KW,S,IH,IW,total; };

__global__ void k_fmap_dir4(DirP p0, DirP p1, DirP p2, DirP p3)
{
    DirP p = (blockIdx.y==0) ? p0 : (blockIdx.y==1) ? p1 : (blockIdx.y==2) ? p2 : p3;
    int i = blockIdx.x*blockDim.x + threadIdx.x;
    if (i >= p.total) return;
    int n = i % p.NTOTP, k = i / p.NTOTP;
    int val = 0;
    if (n < p.NTOT){
        int oh = n / p.OW, ow = n % p.OW;
        int ci = k / p.KPQ, r2 = k - ci*p.KPQ, pp = r2 / p.KW, q = r2 - pp*p.KW;
        val = (ci*p.IH + oh*p.S + pp)*p.IW + ow*p.S + q;
    }
    p.fmap[i] = val;
}

// ---------------------------------------------------------------------------
// Weights: sphere fold avg_pool3(conv3x3) -> 5x5/stride3 f16 [co][KP]; plain cvt
// ---------------------------------------------------------------------------
struct W5P { const float* w3; u16* wh; int CO,CI,KP,total; };

__global__ void k_w5h2(W5P p0, W5P p1)
{
    W5P p = blockIdx.y ? p1 : p0;
    int i = blockIdx.x*blockDim.x + threadIdx.x;
    if (i >= p.total) return;
    int k = i % p.KP, co = i / p.KP;
    float s = 0.f;
    if (k < p.CI*25){
        int ci = k/25, rem = k%25, u = rem/5, v = rem%5;
        const float* w = p.w3 + (co*p.CI + ci)*9;
        int pl0 = max(0, u-2), pl1 = min(2, u);
        int q0 = max(0, v-2), q1 = min(2, v);
        for (int pl=pl0; pl<=pl1; ++pl)
            for (int q=q0; q<=q1; ++q) s += w[pl*3+q];
        s *= (1.0f/9.0f);
    }
    p.wh[i] = f2h(s);
}

struct CvtP { const float* src; u16* dst; int total; };

__global__ void k_wcvt4(CvtP p0, CvtP p1, CvtP p2, CvtP p3)
{
    CvtP p = (blockIdx.y==0) ? p0 : (blockIdx.y==1) ? p1 : (blockIdx.y==2) ? p2 : p3;
    int i = blockIdx.x*blockDim.x + threadIdx.x;
    if (i < p.total) p.dst[i] = f2h(p.src[i]);
}

// ---------------------------------------------------------------------------
// Unified MFMA conv engine, flattened-N. Block = (b, n-tile of NPAD rows);
// 4 waves. Staging is N-FAST: 64 lanes gather 64 consecutive output positions
// at the same k -> addresses march along one input row (~4 lines/wave vs ~64
// for k-fast; R8 diagnosis). fmap is k-major so its reads stay coalesced.
// Intermediates are flat [b][co][NTOT] (consumed via fmap downstream).
// Fragment layout (guide §3, m89-verified): A/B lane&15 = M/N, k=(lane>>4)*8+j;
// D col=lane&15, row=(lane>>4)*4+reg.
// ---------------------------------------------------------------------------
template<typename IN_T,int CO,int NTOT,int NB,int BSTRIDE,
         int KP,int KC,int KCp,int NT_N,int NT_CO>
__global__ __launch_bounds__(256) void k_mconv(
    const IN_T* __restrict__ in, const int* __restrict__ fmap,
    const u16* __restrict__ wh,
    const float* __restrict__ bg, const float* __restrict__ bb,
    const float* __restrict__ bm, const float* __restrict__ bv,
    u16* __restrict__ out)
{
    constexpr int NPAD  = NT_N*16;
    constexpr int NTOTP = NB*NPAD;
    constexpr int TPW   = (NT_N*NT_CO)/4;
    static_assert((NT_N*NT_CO) % 4 == 0, "tiles must split across 4 waves");
    static_assert(KP % KC == 0, "K chunking must divide");
    static_assert(KCp % 8 == 0, "16B-aligned half8 rows");
    static_assert((NPAD & (NPAD-1)) == 0, "NPAD pow2 for lane masking");
    __shared__ __align__(16) u16 sA[NPAD*KCp];
    __shared__ __align__(16) u16 sB[CO*KCp];

    int b  = blockIdx.x / NB;
    int n0 = (blockIdx.x % NB)*NPAD;
    int tid = threadIdx.x;
    const IN_T* xb = in + (size_t)b*BSTRIDE;
    int w = tid >> 6, lane = tid & 63, l15 = lane & 15, l4 = lane >> 4;
    int nt = w % NT_N;
    f32x4 acc[TPW];
    #pragma unroll
    for (int j=0;j<TPW;++j) acc[j] = (f32x4){0.f,0.f,0.f,0.f};

    for (int kc0 = 0; kc0 < KP; kc0 += KC){
        if (kc0) __syncthreads();
        // stage A: n-fast im2col gather (2 adjacent k per thread -> u32 write)
        constexpr int PAIRS = NPAD*(KC/2);
        for (int i = tid; i < PAIRS; i += 256){
            int n = i & (NPAD-1);
            int k = (i / NPAD)*2;
            const int* fr = fmap + (size_t)(kc0 + k)*NTOTP + n0 + n;
            int i0 = fr[0];
            int i1 = fr[NTOTP];
            u16 v0, v1;
            if constexpr (sizeof(IN_T)==4){ v0 = f2h(xb[i0]); v1 = f2h(xb[i1]); }
            else                          { v0 = xb[i0];      v1 = xb[i1]; }
            *reinterpret_cast<u32*>(&sA[n*KCp + k]) = (u32)v0 | ((u32)v1 << 16);
        }
        // stage B: weights, contiguous 16B copies
        for (int i = tid; i < CO*KC/8; i += 256){
            int co = i / (KC/8), j = i % (KC/8);
            uint4 v = *reinterpret_cast<const uint4*>(wh + (size_t)co*KP + kc0 + j*8);
            *reinterpret_cast<uint4*>(&sB[co*KCp + j*8]) = v;
        }
        __syncthreads();
        #pragma unroll
        for (int ks = 0; ks < KC/32; ++ks){
            half8 a = *reinterpret_cast<const half8*>(&sA[(nt*16 + l15)*KCp + ks*32 + l4*8]);
            #pragma unroll
            for (int j=0;j<TPW;++j){
                int ct = (w + j*4)/NT_N;
                half8 bf = *reinterpret_cast<const half8*>(&sB[(ct*16 + l15)*KCp + ks*32 + l4*8]);
                acc[j] = __builtin_amdgcn_mfma_f32_16x16x32_f16(a, bf, acc[j], 0, 0, 0);
            }
        }
    }
    #pragma unroll
    for (int j=0;j<TPW;++j){
        int ct = (w + j*4)/NT_N;
        int co = ct*16 + l15;
        float inv = bg[co]*rsqrtf(bv[co]+1e-5f);
        float shv = bb[co] - bm[co]*inv;
        size_t ob = (size_t)(b*CO + co)*NTOT;
        #pragma unroll
        for (int r=0;r<4;++r){
            int gn = n0 + nt*16 + l4*4 + r;
            if (gn < NTOT) out[ob + gn] = f2h(lrelu_f(fmaf(acc[j][r], inv, shv)));
        }
    }
}

// ---------------------------------------------------------------------------
// fused = lrelu(h5_flat @ proj_w.T + v @ vproj_w.T + vproj_b)   (h5 is f16)
// ---------------------------------------------------------------------------
__global__ __launch_bounds__(256) void k_head(
    const u16* __restrict__ h5, const float* __restrict__ vin,
    const float* __restrict__ proj_w, const float* __restrict__ vproj_w,
    const float* __restrict__ vproj_b, float* __restrict__ fused)
{
    __shared__ __align__(16) float sh[2560];
    __shared__ float sv[9];
    int b = blockIdx.x, tid = threadIdx.x;
    for (int i = tid; i < 2560; i += 256) sh[i] = h2f(h5[(size_t)b*2560 + i]);
    if (tid < 9) sv[tid] = vin[b*9 + tid];
    __syncthreads();
    const float* pw = proj_w + (size_t)tid*2560;
    float acc = 0.f;
    for (int k=0;k<2560;k+=4){
        float4 s4 = *reinterpret_cast<const float4*>(sh+k);
        float4 w4 = *reinterpret_cast<const float4*>(pw+k);
        acc = fmaf(s4.x,w4.x, fmaf(s4.y,w4.y, fmaf(s4.z,w4.z, fmaf(s4.w,w4.w, acc))));
    }
    float av = 0.f;
    #pragma unroll
    for (int k=0;k<9;++k) av += sv[k]*vproj_w[tid*9+k];
    fused[b*256+tid] = lrelu_f(acc + av + vproj_b[tid]);
}

// ---------------------------------------------------------------------------
// GRU cell
// ---------------------------------------------------------------------------
__global__ __launch_bounds__(256) void k_gru(
    const float* __restrict__ fused, const float* __restrict__ hx,
    const float* __restrict__ wih, const float* __restrict__ whh,
    const float* __restrict__ bih, const float* __restrict__ bhh,
    float* __restrict__ hx_new)
{
    __shared__ __align__(16) float sf[256];
    __shared__ __align__(16) float shx[256];
    int b = blockIdx.x, j = threadIdx.x;
    sf[j]  = fused[b*256+j];
    shx[j] = hx[b*256+j];
    __syncthreads();
    float ga[3], gb[3];
    #pragma unroll
    for (int gi=0; gi<3; ++gi){
        const float* wi = wih + ((size_t)gi*256 + j)*256;
        const float* wh = whh + ((size_t)gi*256 + j)*256;
        float a = 0.f, c = 0.f;
        for (int k=0;k<256;k+=4){
            float4 f4  = *reinterpret_cast<const float4*>(sf+k);
            float4 h4  = *reinterpret_cast<const float4*>(shx+k);
            float4 wi4 = *reinterpret_cast<const float4*>(wi+k);
            float4 wh4 = *reinterpret_cast<const float4*>(wh+k);
            a = fmaf(f4.x,wi4.x, fmaf(f4.y,wi4.y, fmaf(f4.z,wi4.z, fmaf(f4.w,wi4.w, a))));
            c = fmaf(h4.x,wh4.x, fmaf(h4.y,wh4.y, fmaf(h4.z,wh4.z, fmaf(h4.w,wh4.w, c))));
        }
        ga[gi] = a + bih[gi*256+j];
        gb[gi] = c + bhh[gi*256+j];
    }
    float r = 1.f/(1.f+expf(-(ga[0]+gb[0])));
    float z = 1.f/(1.f+expf(-(ga[1]+gb[1])));
    float n = tanhf(ga[2] + r*gb[2]);
    hx_new[b*256+j] = (1.f-z)*n + z*shx[j];
}

// act = lrelu(hx_new) @ fc_w.T
__global__ void k_act(const float* __restrict__ hx_new, const float* __restrict__ fc_w,
                      float* __restrict__ act)
{
    int t = blockIdx.x*blockDim.x + threadIdx.x;
    if (t >= 1024) return;
    int b = t >> 2, o = t & 3;
    const float* h = hx_new + b*256;
    const float* w = fc_w + o*256;
    float acc = 0.f;
    for (int k=0;k<256;++k) acc = fmaf(lrelu_f(h[k]), w[k], acc);
    act[t] = acc;
}

extern "C" void kernel_launch(void* const* d_in, const int* in_sizes, int n_in,
                              void* d_out, int out_size, void* d_ws, size_t ws_size,
                              hipStream_t stream)
{
    const float* x      = (const float*)d_in[0];
    const float* vin    = (const float*)d_in[1];
    const float* hx     = (const float*)d_in[2];
    const float* sc0_w  = (const float*)d_in[3];
    const float* bn0g   = (const float*)d_in[4];
    const float* bn0b   = (const float*)d_in[5];
    const float* bn0m   = (const float*)d_in[6];
    const float* bn0v   = (const float*)d_in[7];
    const float* sc1_w  = (const float*)d_in[8];
    const float* bn1g   = (const float*)d_in[9];
    const float* bn1b   = (const float*)d_in[10];
    const float* bn1m   = (const float*)d_in[11];
    const float* bn1v   = (const float*)d_in[12];
    const float* c2_w   = (const float*)d_in[13];
    const float* bn2g   = (const float*)d_in[14];
    const float* bn2b   = (const float*)d_in[15];
    const float* bn2m   = (const float*)d_in[16];
    const float* bn2v   = (const float*)d_in[17];
    const float* c3_w   = (const float*)d_in[18];
    const float* bn3g   = (const float*)d_in[19];
    const float* bn3b   = (const float*)d_in[20];
    const float* bn3m   = (const float*)d_in[21];
    const float* bn3v   = (const float*)d_in[22];
    const float* c4_w   = (const float*)d_in[23];
    const float* bn4g   = (const float*)d_in[24];
    const float* bn4b   = (const float*)d_in[25];
    const float* bn4m   = (const float*)d_in[26];
    const float* bn4v   = (const float*)d_in[27];
    const float* c5_w   = (const float*)d_in[28];
    const float* bn5g   = (const float*)d_in[29];
    const float* bn5b   = (const float*)d_in[30];
    const float* bn5m   = (const float*)d_in[31];
    const float* bn5v   = (const float*)d_in[32];
    const float* proj_w = (const float*)d_in[33];
    const float* vproj_w= (const float*)d_in[34];
    const float* vproj_b= (const float*)d_in[35];
    const float* gru_wih= (const float*)d_in[36];
    const float* gru_whh= (const float*)d_in[37];
    const float* gru_bih= (const float*)d_in[38];
    const float* gru_bhh= (const float*)d_in[39];
    const float* fc_w   = (const float*)d_in[40];

    char* base = (char*)d_ws;
    size_t off = 0;
    auto alloc = [&](size_t bytes)->char*{
        char* p = base + off; off += (bytes + 255) & ~(size_t)255; return p;
    };
    // fmaps are k-major [KP][NTOTP]
    int* fmap0 = (int*)alloc((size_t)160*1984*4);
    int* fmap1 = (int*)alloc((size_t)800*480*4);
    int* fmap2 = (int*)alloc((size_t)576*384*4);
    int* fmap3 = (int*)alloc((size_t)256*96*4);
    int* fmap4 = (int*)alloc((size_t)576*48*4);
    int* fmap5 = (int*)alloc((size_t)1152*32*4);
    u16* wb0  = (u16*)alloc(32*160*2);
    u16* wb1  = (u16*)alloc(64*800*2);
    u16* wb2  = (u16*)alloc((size_t)64*576*2);
    u16* wb3  = (u16*)alloc((size_t)64*256*2);
    u16* wb4  = (u16*)alloc((size_t)128*576*2);
    u16* wb5  = (u16*)alloc((size_t)128*1152*2);
    u16* h0   = (u16*)alloc((size_t)256*32*1953*2);
    u16* h1   = (u16*)alloc((size_t)256*64*465*2);
    u16* h2   = (u16*)alloc((size_t)256*64*377*2);
    u16* h3   = (u16*)alloc((size_t)256*64*84*2);
    u16* h4   = (u16*)alloc((size_t)256*128*48*2);
    u16* h5   = (u16*)alloc((size_t)256*128*20*2);
    float* fused = (float*)alloc((size_t)65536*4);

    // ---- one-time precompute (4 launches) ----
    // sphere fmaps: {fmap,OW,NTOT,NTOTP,K,KP,Wo,H,W,IPLANE,total}
    SphP s0 = { fmap0, 63, 1953, 1984, 150, 160, 64, 64, 128, 8192, 160*1984 };
    SphP s1 = { fmap1, 31,  465,  480, 800, 800, 32, 31,  63, 1953, 800*480 };
    k_fmap_sph2<<<dim3(1500,2), 256, 0, stream>>>(s0, s1);
    // direct fmaps: {fmap,OW,NTOT,NTOTP,K,KPQ,KW,S,IH,IW,total}
    DirP d2 = { fmap2, 29, 377, 384,  576, 9, 3, 1, 15, 31, 576*384 };
    DirP d3 = { fmap3, 14,  84,  96,  256, 4, 2, 2, 13, 29, 256*96 };
    DirP d4 = { fmap4, 12,  48,  48,  576, 9, 3, 1,  6, 14, 576*48 };
    DirP d5 = { fmap5, 10,  20,  32, 1152, 9, 3, 1,  4, 12, 1152*32 };
    k_fmap_dir4<<<dim3(864,4), 256, 0, stream>>>(d2, d3, d4, d5);
    W5P w0 = { sc0_w, wb0, 32,  6, 160, 32*160 };
    W5P w1 = { sc1_w, wb1, 64, 32, 800, 64*800 };
    k_w5h2<<<dim3(200,2), 256, 0, stream>>>(w0, w1);
    CvtP c2 = { c2_w, wb2, 36864 };
    CvtP c3 = { c3_w, wb3, 16384 };
    CvtP c4 = { c4_w, wb4, 73728 };
    CvtP c5 = { c5_w, wb5, 147456 };
    k_wcvt4<<<dim3(576,4), 256, 0, stream>>>(c2, c3, c4, c5);

    // ---- backbone (MFMA f16, n-fast fmap staging) ----
    // k_mconv<IN_T,CO,NTOT,NB,BSTRIDE,KP,KC,KCp,NT_N,NT_CO>
    k_mconv<float,32,1953,31,49152,160,160,168,4,2>
        <<<256*31, 256, 0, stream>>>(x,  fmap0, wb0, bn0g,bn0b,bn0m,bn0v, h0);
    k_mconv<u16,64,465,15,62496,800,160,168,2,4>
        <<<256*15, 256, 0, stream>>>(h0, fmap1, wb1, bn1g,bn1b,bn1m,bn1v, h1);
    k_mconv<u16,64,377,12,29760,576,192,200,2,4>
        <<<256*12, 256, 0, stream>>>(h1, fmap2, wb2, bn2g,bn2b,bn2m,bn2v, h2);
    k_mconv<u16,64,84,3,24128,256,128,136,2,4>
        <<<256*3,  256, 0, stream>>>(h2, fmap3, wb3, bn3g,bn3b,bn3m,bn3v, h3);
    k_mconv<u16,128,48,3,5376,576,192,200,1,8>
        <<<256*3,  256, 0, stream>>>(h3, fmap4, wb4, bn4g,bn4b,bn4m,bn4v, h4);
    k_mconv<u16,128,20,2,6144,1152,192,200,1,8>
        <<<256*2,  256, 0, stream>>>(h4, fmap5, wb5, bn5g,bn5b,bn5m,bn5v, h5);

    // ---- head ----
    k_head<<<256, 256, 0, stream>>>(h5, vin, proj_w, vproj_w, vproj_b, fused);
    float* outp = (float*)d_out;
    k_gru<<<256, 256, 0, stream>>>(fused, hx, gru_wih, gru_whh, gru_bih, gru_bhh, outp + 1024);
    k_act<<<4, 256, 0, stream>>>(outp + 1024, fc_w, outp);
}